// Round 2
// baseline (241.586 us; speedup 1.0000x reference)
//
#include <hip/hip_runtime.h>

// Problem constants (Graphormer node feature + SAGE conv)
#define G_     64
#define NODES_ 511
#define NN_    512          // NODES + 1 (graph token row 0)
#define H_     768
#define E_     4096
#define NTYPE  5            // graph_emb + node_emb[0..3]
#define S_     32           // blocks per graph in fused kernel
#define ROWS_  (NN_ / S_)   // 16 rows per block

typedef float f32x4 __attribute__((ext_vector_type(4)));

// ---------------------------------------------------------------------------
// Kernel 1: projection tables.
//   P_l[t] = emb_t @ W_l^T
//   P_r[t] = emb_t @ W_r^T + b_l     (b_l folded)
// One wave per (m, j): the W row is read ONCE and reused for all 5 embedding
// types (5x less W traffic than wave-per-(m,t,j)). 1536 waves = 192 x 512.
// ---------------------------------------------------------------------------
__global__ __launch_bounds__(512)
void proj_kernel(const float* __restrict__ node_emb,   // (4, H)
                 const float* __restrict__ graph_emb,  // (1, H)
                 const float* __restrict__ W_l,        // (H, H)
                 const float* __restrict__ b_l,        // (H,)
                 const float* __restrict__ W_r,        // (H, H)
                 float* __restrict__ P_l,              // (5, H)
                 float* __restrict__ P_r)              // (5, H)
{
    int wave = blockIdx.x * 8 + (threadIdx.x >> 6);    // 0..1535
    int lane = threadIdx.x & 63;
    int m = wave / H_;                                 // 0 -> W_l, 1 -> W_r
    int j = wave % H_;

    const float* W = ((m == 0) ? W_l : W_r) + (size_t)j * H_;
    int k0 = lane * 4;
    f32x4 w0 = *(const f32x4*)(W + k0);
    f32x4 w1 = *(const f32x4*)(W + k0 + 256);
    f32x4 w2 = *(const f32x4*)(W + k0 + 512);

    float acc[NTYPE];
    #pragma unroll
    for (int t = 0; t < NTYPE; ++t) {
        const float* emb = (t == 0) ? graph_emb : (node_emb + (size_t)(t - 1) * H_);
        f32x4 e0 = *(const f32x4*)(emb + k0);
        f32x4 e1 = *(const f32x4*)(emb + k0 + 256);
        f32x4 e2 = *(const f32x4*)(emb + k0 + 512);
        acc[t] = w0.x*e0.x + w0.y*e0.y + w0.z*e0.z + w0.w*e0.w
               + w1.x*e1.x + w1.y*e1.y + w1.z*e1.z + w1.w*e1.w
               + w2.x*e2.x + w2.y*e2.y + w2.z*e2.z + w2.w*e2.w;
    }
    #pragma unroll
    for (int t = 0; t < NTYPE; ++t) {
        #pragma unroll
        for (int off = 32; off; off >>= 1)
            acc[t] += __shfl_xor(acc[t], off, 64);
    }

    if (lane == 0) {
        if (m == 0) {
            #pragma unroll
            for (int t = 0; t < NTYPE; ++t) P_l[t * H_ + j] = acc[t];
        } else {
            float b = b_l[j];
            #pragma unroll
            for (int t = 0; t < NTYPE; ++t) P_r[t * H_ + j] = acc[t] + b;
        }
    }
}

// ---------------------------------------------------------------------------
// Kernel 2 (fused hist + output): 32 blocks per graph, each owns 16 rows.
// Phase 1: scan this graph's dst stream (16 KB, L2-hit after first block),
//          LDS-histogram only edges landing in our 16 rows (80-int hist).
// Phase 2: per-row coefficients a_t = cnt_t / max(deg,1) and node type -> LDS.
// Phase 3: wave-per-row writes. P_l (5 rows) is preloaded into registers once
//          per thread (15 f32x4); per row only P_r[type] + emb[type] are read
//          from L1. Plain stores (NOT nontemporal): the rocclr fill kernel
//          demonstrates 6.46 TB/s with plain streaming stores on this buffer.
// ---------------------------------------------------------------------------
__global__ __launch_bounds__(256)
void fused_kernel(const int* __restrict__ nodes,       // (G, NODES)
                  const int* __restrict__ edges,       // (G, 2, E)
                  const float* __restrict__ node_emb,  // (4, H)
                  const float* __restrict__ graph_emb, // (1, H)
                  const float* __restrict__ P_l,       // (5, H)
                  const float* __restrict__ P_r,       // (5, H)
                  float* __restrict__ gnf,             // (G, NN, H)
                  float* __restrict__ gef)             // (G, NN, H)
{
    int g  = blockIdx.x >> 5;          // / S_
    int s  = blockIdx.x & (S_ - 1);
    int lo = s * ROWS_;                // first row n handled by this block
    int t  = threadIdx.x;

    __shared__ int   hist[ROWS_ * NTYPE];   // 80 ints
    __shared__ float a_s[ROWS_][NTYPE];     // cnt_t * inv(deg)
    __shared__ int   type_s[ROWS_];

    if (t < ROWS_ * NTYPE) hist[t] = 0;
    __syncthreads();

    const int* eg = edges + (size_t)g * 2 * E_;
    const int* ng = nodes + (size_t)g * NODES_;

    #pragma unroll
    for (int i = 0; i < E_ / 256; ++i) {    // 16 edges per thread
        int e   = t + i * 256;
        int dst = eg[E_ + e];               // coalesced
        unsigned d = (unsigned)(dst - lo);
        if (d < ROWS_) {
            int src  = eg[e];
            int type = (src == 0) ? 0 : (ng[src - 1] + 1);
            atomicAdd(&hist[d * NTYPE + type], 1);
        }
    }
    __syncthreads();

    if (t < ROWS_) {
        float c0 = (float)hist[t * NTYPE + 0];
        float c1 = (float)hist[t * NTYPE + 1];
        float c2 = (float)hist[t * NTYPE + 2];
        float c3 = (float)hist[t * NTYPE + 3];
        float c4 = (float)hist[t * NTYPE + 4];
        float inv = 1.0f / fmaxf(c0 + c1 + c2 + c3 + c4, 1.0f);
        a_s[t][0] = c0 * inv;
        a_s[t][1] = c1 * inv;
        a_s[t][2] = c2 * inv;
        a_s[t][3] = c3 * inv;
        a_s[t][4] = c4 * inv;
        int n = lo + t;
        type_s[t] = (n == 0) ? 0 : (ng[n - 1] + 1);
    }
    __syncthreads();

    // ---- write phase: wave w handles rows {rr*4 + w}, lane covers 3 chunks ----
    int w    = t >> 6;
    int lane = t & 63;
    int k0   = lane * 4;

    // Preload all of P_l into registers: 5 rows x 3 chunks = 15 f32x4.
    f32x4 pl[NTYPE][3];
    #pragma unroll
    for (int tt = 0; tt < NTYPE; ++tt) {
        #pragma unroll
        for (int c = 0; c < 3; ++c)
            pl[tt][c] = *(const f32x4*)(P_l + (size_t)tt * H_ + k0 + c * 256);
    }

    size_t base = ((size_t)g * NN_ + lo) * H_;

    #pragma unroll
    for (int rr = 0; rr < ROWS_ / 4; ++rr) {
        int r  = rr * 4 + w;
        int ty = type_s[r];
        float a0 = a_s[r][0], a1 = a_s[r][1], a2 = a_s[r][2],
              a3 = a_s[r][3], a4 = a_s[r][4];
        const float* prr = P_r + (size_t)ty * H_;
        const float* er  = (ty == 0) ? graph_emb : (node_emb + (size_t)(ty - 1) * H_);
        size_t roff = base + (size_t)r * H_ + k0;

        #pragma unroll
        for (int c = 0; c < 3; ++c) {
            f32x4 pr = *(const f32x4*)(prr + k0 + c * 256);
            f32x4 ev = *(const f32x4*)(er  + k0 + c * 256);
            f32x4 o  = a0 * pl[0][c] + a1 * pl[1][c] + a2 * pl[2][c]
                     + a3 * pl[3][c] + a4 * pl[4][c] + pr;
            *(f32x4*)(gnf + roff + c * 256) = ev;
            *(f32x4*)(gef + roff + c * 256) = o;
        }
    }
}

// ---------------------------------------------------------------------------
extern "C" void kernel_launch(void* const* d_in, const int* in_sizes, int n_in,
                              void* d_out, int out_size, void* d_ws, size_t ws_size,
                              hipStream_t stream)
{
    const int*   input_nodes = (const int*)d_in[0];   // (G, NODES) int32
    const int*   input_edges = (const int*)d_in[1];   // (G, 2, E)  int32
    const float* node_emb    = (const float*)d_in[2]; // (4, H)
    const float* graph_emb   = (const float*)d_in[3]; // (1, H)
    const float* W_l         = (const float*)d_in[4]; // (H, H)
    const float* b_l         = (const float*)d_in[5]; // (H,)
    const float* W_r         = (const float*)d_in[6]; // (H, H)

    float* gnf = (float*)d_out;                       // output 0: (G, NN, H)
    float* gef = gnf + (size_t)G_ * NN_ * H_;         // output 1: (G, NN, H)

    float* P_l = (float*)d_ws;                        // 5*H floats
    float* P_r = P_l + NTYPE * H_;                    // 5*H floats

    // Projection tables: 1536 waves (one per (m, j)), 192 blocks x 512.
    proj_kernel<<<(2 * H_) / 8, 512, 0, stream>>>(
        node_emb, graph_emb, W_l, b_l, W_r, P_l, P_r);

    // Fused histogram + outputs: G*S = 2048 blocks x 256 threads.
    fused_kernel<<<G_ * S_, 256, 0, stream>>>(
        input_nodes, input_edges, node_emb, graph_emb, P_l, P_r, gnf, gef);
}